// Round 10
// baseline (372.513 us; speedup 1.0000x reference)
//
#include <hip/hip_runtime.h>
#include <math.h>

#define NW      239            // (30720 - 256)/128 + 1
#define NBINS   129
#define NSAMP   30720
#define HOP     128
#define NFRAMES (1472 * NW)    // 351,808 = 64*23*239
#define NWAVES  8192
#define FPB     43             // ceil(NFRAMES / NWAVES)
#define WPB     4              // waves per block
#define NBLOCKS (NWAVES / WPB) // 2048

// 256-thread blocks = 4 independent 64-lane waves; each wave owns FPB
// consecutive frames. Frame-invariant window/twiddles hoisted (round 8).
// NEW: 2 frames per iteration, chains interleaved -> per-wave ILP covers
// ds_swizzle / lgkmcnt / VMEM latency (kernel is latency-bound, r9 analysis).
__global__ __launch_bounds__(256) void stft_kernel(const float* __restrict__ sig,
                                                   float* __restrict__ out) {
    const int l  = threadIdx.x & 63;       // lane
    const int wv = threadIdx.x >> 6;       // wave id within block

    __shared__ __align__(8) float zRA[WPB][128], zIA[WPB][128];
    __shared__ __align__(8) float zRB[WPB][128], zIB[WPB][128];
    float* __restrict__ zra = zRA[wv];
    float* __restrict__ zia = zIA[wv];
    float* __restrict__ zrb = zRB[wv];
    float* __restrict__ zib = zIB[wv];

    // ======== frame-invariant per-lane constants (computed ONCE) ========
    const float w0 = 0.5f - 0.5f * cospif((float)(4 * l)       * (1.0f / 255.0f));
    const float w1 = 0.5f - 0.5f * cospif((float)(4 * l + 2)   * (1.0f / 255.0f));
    const float w2 = 0.5f - 0.5f * cospif((float)(4 * l + 256) * (1.0f / 255.0f));
    const float w3 = 0.5f - 0.5f * cospif((float)(4 * l + 258) * (1.0f / 255.0f));
    float c64, s64;  sincospif((float)l * (1.0f / 64.0f), &s64, &c64);
    float c32, s32;  sincospif((float)(l & 31) * (1.0f / 32.0f), &s32, &c32);
    float c16, s16;  sincospif((float)(l & 15) * (1.0f / 16.0f), &s16, &c16);
    float c8,  s8;   sincospif((float)(l & 7)  * (1.0f / 8.0f),  &s8,  &c8);
    float c4,  s4;   sincospif((float)(l & 3)  * (1.0f / 4.0f),  &s4,  &c4);
    float cu0, su0;  sincospif((float)l        * (1.0f / 128.0f), &su0, &cu0);  // k=l
    float cu1, su1;  sincospif((float)(l + 64) * (1.0f / 128.0f), &su1, &cu1);  // k=l+64
    const int pn  = (int)(__brev((unsigned)l) >> 26);  // brev6(l)
    const int km0 = (128 - l) & 127;
    const int km1 = 64 - l;

    const int g    = blockIdx.x * WPB + wv;
    const int f0   = g * FPB;
    const int fe   = f0 + FPB;
    const int fend = fe < NFRAMES ? fe : NFRAMES;

    for (int f = f0; f < fend; f += 2) {
        const int fB   = (f + 1 < fend) ? f + 1 : f;   // odd tail: duplicate
        const int rowA = f / NW,  wA = f - rowA * NW;
        const int rowB = fB / NW, wB = fB - rowB * NW;
        const float* __restrict__ srcA = sig + (size_t)rowA * NSAMP + (size_t)wA * HOP;
        const float* __restrict__ srcB = sig + (size_t)rowB * NSAMP + (size_t)wB * HOP;

        // ---- issue all 4 global loads up front
        float2 a0 = *reinterpret_cast<const float2*>(srcA + 2 * l);
        float2 a1 = *reinterpret_cast<const float2*>(srcA + 2 * l + 128);
        float2 b0 = *reinterpret_cast<const float2*>(srcB + 2 * l);
        float2 b1 = *reinterpret_cast<const float2*>(srcB + 2 * l + 128);

        float vA0r = a0.x * w0, vA0i = a0.y * w1;
        float vA1r = a1.x * w2, vA1i = a1.y * w3;
        float vB0r = b0.x * w0, vB0i = b0.y * w1;
        float vB1r = b1.x * w2, vB1i = b1.y * w3;

        // ---- stage h=64 (lane-local), both frames
        {
            float tr, ti;
            tr = vA0r - vA1r; ti = vA0i - vA1i; vA0r += vA1r; vA0i += vA1i;
            vA1r = tr * c64 + ti * s64; vA1i = ti * c64 - tr * s64;
            tr = vB0r - vB1r; ti = vB0i - vB1i; vB0r += vB1r; vB0i += vB1i;
            vB1r = tr * c64 + ti * s64; vB1i = ti * c64 - tr * s64;
        }

        // ---- stages h = 32,16,8,4: 8 shfls issued together, then math
        #define XST2(m, cc, ss)                                               \
        {                                                                     \
            const bool up = (l & (m)) != 0;                                   \
            const float qA0r = __shfl_xor(vA0r, (m)), qA0i = __shfl_xor(vA0i, (m)); \
            const float qA1r = __shfl_xor(vA1r, (m)), qA1i = __shfl_xor(vA1i, (m)); \
            const float qB0r = __shfl_xor(vB0r, (m)), qB0i = __shfl_xor(vB0i, (m)); \
            const float qB1r = __shfl_xor(vB1r, (m)), qB1i = __shfl_xor(vB1i, (m)); \
            float dr, di, wr, wi;                                             \
            dr = qA0r - vA0r; di = qA0i - vA0i;                               \
            wr = dr * (cc) + di * (ss); wi = di * (cc) - dr * (ss);           \
            vA0r = up ? wr : (vA0r + qA0r); vA0i = up ? wi : (vA0i + qA0i);   \
            dr = qA1r - vA1r; di = qA1i - vA1i;                               \
            wr = dr * (cc) + di * (ss); wi = di * (cc) - dr * (ss);           \
            vA1r = up ? wr : (vA1r + qA1r); vA1i = up ? wi : (vA1i + qA1i);   \
            dr = qB0r - vB0r; di = qB0i - vB0i;                               \
            wr = dr * (cc) + di * (ss); wi = di * (cc) - dr * (ss);           \
            vB0r = up ? wr : (vB0r + qB0r); vB0i = up ? wi : (vB0i + qB0i);   \
            dr = qB1r - vB1r; di = qB1i - vB1i;                               \
            wr = dr * (cc) + di * (ss); wi = di * (cc) - dr * (ss);           \
            vB1r = up ? wr : (vB1r + qB1r); vB1i = up ? wi : (vB1i + qB1i);   \
        }
        XST2(32, c32, s32)
        XST2(16, c16, s16)
        XST2(8,  c8,  s8)
        XST2(4,  c4,  s4)
        #undef XST2

        // ---- stage h=2: twiddle 1 (j=0) or -i (j=1)
        {
            const bool up = (l & 2) != 0;
            const bool j1 = (l & 1) != 0;
            const float qA0r = __shfl_xor(vA0r, 2), qA0i = __shfl_xor(vA0i, 2);
            const float qA1r = __shfl_xor(vA1r, 2), qA1i = __shfl_xor(vA1i, 2);
            const float qB0r = __shfl_xor(vB0r, 2), qB0i = __shfl_xor(vB0i, 2);
            const float qB1r = __shfl_xor(vB1r, 2), qB1i = __shfl_xor(vB1i, 2);
            float dr, di, wr, wi;
            dr = qA0r - vA0r; di = qA0i - vA0i;
            wr = j1 ? di : dr; wi = j1 ? -dr : di;
            vA0r = up ? wr : (vA0r + qA0r); vA0i = up ? wi : (vA0i + qA0i);
            dr = qA1r - vA1r; di = qA1i - vA1i;
            wr = j1 ? di : dr; wi = j1 ? -dr : di;
            vA1r = up ? wr : (vA1r + qA1r); vA1i = up ? wi : (vA1i + qA1i);
            dr = qB0r - vB0r; di = qB0i - vB0i;
            wr = j1 ? di : dr; wi = j1 ? -dr : di;
            vB0r = up ? wr : (vB0r + qB0r); vB0i = up ? wi : (vB0i + qB0i);
            dr = qB1r - vB1r; di = qB1i - vB1i;
            wr = j1 ? di : dr; wi = j1 ? -dr : di;
            vB1r = up ? wr : (vB1r + qB1r); vB1i = up ? wi : (vB1i + qB1i);
        }

        // ---- stage h=1: twiddle 1
        {
            const bool up = (l & 1) != 0;
            const float qA0r = __shfl_xor(vA0r, 1), qA0i = __shfl_xor(vA0i, 1);
            const float qA1r = __shfl_xor(vA1r, 1), qA1i = __shfl_xor(vA1i, 1);
            const float qB0r = __shfl_xor(vB0r, 1), qB0i = __shfl_xor(vB0i, 1);
            const float qB1r = __shfl_xor(vB1r, 1), qB1i = __shfl_xor(vB1i, 1);
            vA0r = up ? (qA0r - vA0r) : (vA0r + qA0r);
            vA0i = up ? (qA0i - vA0i) : (vA0i + qA0i);
            vA1r = up ? (qA1r - vA1r) : (vA1r + qA1r);
            vA1i = up ? (qA1i - vA1i) : (vA1i + qA1i);
            vB0r = up ? (qB0r - vB0r) : (vB0r + qB0r);
            vB0i = up ? (qB0i - vB0i) : (vB0i + qB0i);
            vB1r = up ? (qB1r - vB1r) : (vB1r + qB1r);
            vB1i = up ? (qB1i - vB1i) : (vB1i + qB1i);
        }

        // ---- scatter to natural order (separate buffers -> tails overlap)
        reinterpret_cast<float2*>(zra)[pn] = make_float2(vA0r, vA1r);
        reinterpret_cast<float2*>(zia)[pn] = make_float2(vA0i, vA1i);
        reinterpret_cast<float2*>(zrb)[pn] = make_float2(vB0r, vB1r);
        reinterpret_cast<float2*>(zib)[pn] = make_float2(vB0i, vB1i);
        // wave-synchronous LDS; compiler lgkmcnt ordering covers RAW

        // ---- rfft untangle + log-mag store, both frames
        #define FIN(zr_, zi_, optr)                                           \
        {                                                                     \
            {                                                                 \
                float zkr = (zr_)[l],   zki = (zi_)[l];                       \
                float zmr = (zr_)[km0], zmi = (zi_)[km0];                     \
                float er  = 0.5f * (zkr + zmr);                               \
                float ei  = 0.5f * (zki - zmi);                               \
                float orr = 0.5f * (zki + zmi);                               \
                float oi  = -0.5f * (zkr - zmr);                              \
                float Xr = er + cu0 * orr + su0 * oi;                         \
                float Xi = ei + cu0 * oi - su0 * orr;                         \
                float mag = sqrtf(Xr * Xr + Xi * Xi);                         \
                (optr)[l] = __log2f(mag + 1e-8f) * 6.931471805599453f;        \
            }                                                                 \
            {                                                                 \
                float zkr = (zr_)[l + 64], zki = (zi_)[l + 64];               \
                float zmr = (zr_)[km1],    zmi = (zi_)[km1];                  \
                float er  = 0.5f * (zkr + zmr);                               \
                float ei  = 0.5f * (zki - zmi);                               \
                float orr = 0.5f * (zki + zmi);                               \
                float oi  = -0.5f * (zkr - zmr);                              \
                float Xr = er + cu1 * orr + su1 * oi;                         \
                float Xi = ei + cu1 * oi - su1 * orr;                         \
                float mag = sqrtf(Xr * Xr + Xi * Xi);                         \
                (optr)[l + 64] = __log2f(mag + 1e-8f) * 6.931471805599453f;   \
            }                                                                 \
            if (l == 0) {                                                     \
                float Xr = (zr_)[0] - (zi_)[0];                               \
                (optr)[128] = __log2f(fabsf(Xr) + 1e-8f) * 6.931471805599453f;\
            }                                                                 \
        }
        float* __restrict__ oA = out + (size_t)f  * NBINS;
        float* __restrict__ oB = out + (size_t)fB * NBINS;
        FIN(zra, zia, oA)
        FIN(zrb, zib, oB)
        #undef FIN
    }
}

extern "C" void kernel_launch(void* const* d_in, const int* in_sizes, int n_in,
                              void* d_out, int out_size, void* d_ws, size_t ws_size,
                              hipStream_t stream) {
    const float* sig = (const float*)d_in[0];
    float* out = (float*)d_out;
    (void)in_sizes; (void)n_in; (void)out_size; (void)d_ws; (void)ws_size;
    stft_kernel<<<dim3(NBLOCKS), dim3(256), 0, stream>>>(sig, out);
}